// Round 1
// baseline (295.648 us; speedup 1.0000x reference)
//
#include <hip/hip_runtime.h>
#include <cfloat>

// Problem constants (VectorQuantizer): inputs [64,32,32,64] f32, embeddings [2048,64] f32
#define N_TOTAL 65536
#define DIM     64
#define NEMB    2048
#define BM      128       // rows per block
#define BK      128       // embeddings per K-tile
#define LSTRIDE 132       // LDS row stride in floats (128 + 4 pad, multiple of 4 for b128 alignment)

// ---------------------------------------------------------------------------
// Kernel 1: per-embedding squared norms -> d_ws  (2048 floats)
// ---------------------------------------------------------------------------
__global__ void enorm_kernel(const float* __restrict__ emb, float* __restrict__ enorm) {
    int k = blockIdx.x * blockDim.x + threadIdx.x;   // grid sized exactly to NEMB
    const float4* row = (const float4*)(emb + (size_t)k * DIM);
    float s = 0.f;
#pragma unroll
    for (int i = 0; i < DIM / 4; ++i) {
        float4 v = row[i];
        s = fmaf(v.x, v.x, s);
        s = fmaf(v.y, v.y, s);
        s = fmaf(v.z, v.z, s);
        s = fmaf(v.w, v.w, s);
    }
    enorm[k] = s;
}

// ---------------------------------------------------------------------------
// Kernel 2: main VQ — distances via GEMM-style register tiling + running argmin
//   score(row, k) = ||e_k||^2 - 2 * dot(x_row, e_k)      (||x||^2 dropped: row-constant)
// Thread layout: 256 threads = (ty 0..15) x (tx 0..15); thread tile = 8 rows x 8 cols.
//   rows: ty*8 + i
//   cols within tile: {4*tx + j, j<4} U {64 + 4*tx + j}   (interleaved to dodge LDS
//   bank collisions on the e-fragment reads; tie-break handled by index compare)
// LDS: tiles stored transposed [d][row] so inner-loop reads are contiguous b128.
// ---------------------------------------------------------------------------
__global__ __launch_bounds__(256, 2) void vq_main_kernel(
        const float* __restrict__ x,
        const float* __restrict__ emb,
        const float* __restrict__ enorm,
        float* __restrict__ quant,
        float* __restrict__ idx_out) {

    __shared__ float Xs[DIM][LSTRIDE];
    __shared__ float Es[DIM][LSTRIDE];

    const int t    = threadIdx.x;
    const int tx   = t & 15;
    const int ty   = t >> 4;
    const int row0 = blockIdx.x * BM;

    // ---- stage X tile (once per block), transposed ----
    {
        const int c4 = t & 15;   // float4 index along D
        const int rr = t >> 4;   // row within pass
#pragma unroll
        for (int p = 0; p < BM; p += 16) {
            const int r = p + rr;
            float4 v = *(const float4*)(x + (size_t)(row0 + r) * DIM + c4 * 4);
            Xs[c4 * 4 + 0][r] = v.x;
            Xs[c4 * 4 + 1][r] = v.y;
            Xs[c4 * 4 + 2][r] = v.z;
            Xs[c4 * 4 + 3][r] = v.w;
        }
    }

    float best[8];
    int   besti[8];
#pragma unroll
    for (int i = 0; i < 8; ++i) { best[i] = FLT_MAX; besti[i] = 0; }

    for (int kt = 0; kt < NEMB / BK; ++kt) {
        // ---- stage E tile, transposed ----
        __syncthreads();   // previous iteration's readers done with Es
        {
            const int c4 = t & 15;
            const int rr = t >> 4;
#pragma unroll
            for (int p = 0; p < BK; p += 16) {
                const int r = p + rr;
                float4 v = *(const float4*)(emb + (size_t)(kt * BK + r) * DIM + c4 * 4);
                Es[c4 * 4 + 0][r] = v.x;
                Es[c4 * 4 + 1][r] = v.y;
                Es[c4 * 4 + 2][r] = v.z;
                Es[c4 * 4 + 3][r] = v.w;
            }
        }
        __syncthreads();

        // ---- 128x128 GEMM tile, 8x8 per thread ----
        float acc[8][8];
#pragma unroll
        for (int i = 0; i < 8; ++i)
#pragma unroll
            for (int j = 0; j < 8; ++j) acc[i][j] = 0.f;

#pragma unroll 4
        for (int d = 0; d < DIM; ++d) {
            float4 xa = *(const float4*)&Xs[d][ty * 8];
            float4 xb = *(const float4*)&Xs[d][ty * 8 + 4];
            float4 ea = *(const float4*)&Es[d][tx * 4];
            float4 eb = *(const float4*)&Es[d][64 + tx * 4];
            float xs[8] = {xa.x, xa.y, xa.z, xa.w, xb.x, xb.y, xb.z, xb.w};
            float es[8] = {ea.x, ea.y, ea.z, ea.w, eb.x, eb.y, eb.z, eb.w};
#pragma unroll
            for (int i = 0; i < 8; ++i)
#pragma unroll
                for (int j = 0; j < 8; ++j)
                    acc[i][j] = fmaf(xs[i], es[j], acc[i][j]);
        }

        // ---- score + running min (cols ascending within thread for first-min tie-break) ----
        float en[8];
#pragma unroll
        for (int j = 0; j < 4; ++j) {
            en[j]     = enorm[kt * BK + 4 * tx + j];
            en[4 + j] = enorm[kt * BK + 64 + 4 * tx + j];
        }
#pragma unroll
        for (int i = 0; i < 8; ++i) {
#pragma unroll
            for (int j = 0; j < 8; ++j) {
                const int col = kt * BK + ((j < 4) ? (4 * tx + j) : (64 + 4 * tx + (j - 4)));
                float sc = fmaf(-2.f, acc[i][j], en[j]);
                if (sc < best[i]) { best[i] = sc; besti[i] = col; }
            }
        }
    }

    // ---- butterfly-merge across the 16 tx lanes sharing each row group ----
#pragma unroll
    for (int m = 1; m < 16; m <<= 1) {
#pragma unroll
        for (int i = 0; i < 8; ++i) {
            float ob = __shfl_xor(best[i], m, 64);
            int   oi = __shfl_xor(besti[i], m, 64);
            if (ob < best[i] || (ob == best[i] && oi < besti[i])) {
                best[i] = ob; besti[i] = oi;
            }
        }
    }

    // ---- write indices (as float) ----
    if (tx == 0) {
#pragma unroll
        for (int i = 0; i < 8; ++i)
            idx_out[row0 + ty * 8 + i] = (float)besti[i];
    }

    // ---- write quantized = embeddings[besti] (16 lanes x float4 cover each row) ----
#pragma unroll
    for (int i = 0; i < 8; ++i) {
        float4 v = *(const float4*)(emb + (size_t)besti[i] * DIM + tx * 4);
        *(float4*)(quant + (size_t)(row0 + ty * 8 + i) * DIM + tx * 4) = v;
    }
}

// ---------------------------------------------------------------------------
// Kernel 3: flat_inputs = inputs (straight copy, float4)
// ---------------------------------------------------------------------------
__global__ void copy_kernel(const float4* __restrict__ in, float4* __restrict__ out) {
    int i = blockIdx.x * blockDim.x + threadIdx.x;   // grid sized exactly
    out[i] = in[i];
}

extern "C" void kernel_launch(void* const* d_in, const int* in_sizes, int n_in,
                              void* d_out, int out_size, void* d_ws, size_t ws_size,
                              hipStream_t stream) {
    const float* x   = (const float*)d_in[0];   // [65536, 64]
    const float* emb = (const float*)d_in[1];   // [2048, 64]
    float* out   = (float*)d_out;
    float* quant = out;                               // 4194304 floats
    float* idxf  = out + (size_t)N_TOTAL * DIM;       // 65536 floats
    float* flat  = idxf + N_TOTAL;                    // 4194304 floats
    float* enorm = (float*)d_ws;                      // 2048 floats scratch

    enorm_kernel<<<NEMB / 256, 256, 0, stream>>>(emb, enorm);
    vq_main_kernel<<<N_TOTAL / BM, 256, 0, stream>>>(x, emb, enorm, quant, idxf);
    copy_kernel<<<(N_TOTAL * DIM / 4) / 256, 256, 0, stream>>>((const float4*)x, (float4*)flat);
}